// Round 1
// baseline (1780.825 us; speedup 1.0000x reference)
//
#include <hip/hip_runtime.h>

#define NCELLS 512
#define WORD_SZ 64
#define RHEADS 4
#define BATCH 16
#define TSTEPS 32
#define IFSZ 471
#define EPSC 1e-8f
#define NSTRIPE 16   // link kernel: 16 stripes of 32 rows

// ---------- helpers ----------
__device__ __forceinline__ float wave_sum(float v) {
#pragma unroll
  for (int m = 32; m >= 1; m >>= 1) v += __shfl_xor(v, m, 64);
  return v;
}
__device__ __forceinline__ float wave_max(float v) {
#pragma unroll
  for (int m = 32; m >= 1; m >>= 1) v = fmaxf(v, __shfl_xor(v, m, 64));
  return v;
}
// deterministic block reductions (512 threads = 8 waves)
__device__ __forceinline__ float block_sum(float v, float* s_red, int tid) {
  float w = wave_sum(v);
  if ((tid & 63) == 0) s_red[tid >> 6] = w;
  __syncthreads();
  float tot = 0.f;
#pragma unroll
  for (int i = 0; i < 8; i++) tot += s_red[i];
  __syncthreads();
  return tot;
}
__device__ __forceinline__ float block_max(float v, float* s_red, int tid) {
  float w = wave_max(v);
  if ((tid & 63) == 0) s_red[tid >> 6] = w;
  __syncthreads();
  float tot = s_red[0];
#pragma unroll
  for (int i = 1; i < 8; i++) tot = fmaxf(tot, s_red[i]);
  __syncthreads();
  return tot;
}
__device__ __forceinline__ float softplus_f(float x) {
  return fmaxf(x, 0.f) + log1pf(expf(-fabsf(x)));
}
__device__ __forceinline__ float sigmoid_f(float x) {
  return 1.f / (1.f + expf(-x));
}

// ---------- init ----------
__global__ void init_kernel(float* link, float* mem, float* rw, float* usage,
                            float* prec) {
  size_t i = (size_t)blockIdx.x * blockDim.x + threadIdx.x;
  size_t stride = (size_t)gridDim.x * blockDim.x;
  const size_t nlink = (size_t)BATCH * NCELLS * NCELLS;
  const size_t nmem = (size_t)BATCH * NCELLS * WORD_SZ;
  const size_t nrw = (size_t)BATCH * RHEADS * NCELLS;
  const size_t nu = (size_t)BATCH * NCELLS;
  for (size_t x = i; x < nlink; x += stride) link[x] = 0.f;
  for (size_t x = i; x < nmem; x += stride) mem[x] = 0.f;
  for (size_t x = i; x < nrw; x += stride) rw[x] = 1.f / NCELLS;
  for (size_t x = i; x < nu; x += stride) { usage[x] = 0.f; prec[x] = 0.f; }
}

// ---------- interface: GEMM (B*T,512)x(512,471) + activations ----------
__global__ __launch_bounds__(512) void iface_kernel(
    const float* __restrict__ ctrl, const float* __restrict__ W,
    const float* __restrict__ bif, float* __restrict__ iface) {
  int bt = blockIdx.x;
  int tid = threadIdx.x;
  __shared__ float s_ctrl[512];
  __shared__ float s_v[IFSZ];
  s_ctrl[tid] = ctrl[(size_t)bt * 512 + tid];
  __syncthreads();
  if (tid < IFSZ) {
    float acc = bif[tid];
#pragma unroll 8
    for (int k = 0; k < 512; k++) acc = fmaf(s_ctrl[k], W[(size_t)k * IFSZ + tid], acc);
    s_v[tid] = acc;
  }
  __syncthreads();
  if (tid < IFSZ) {
    float v = s_v[tid];
    float o;
    if (tid < 256) o = v;                       // read keys (raw)
    else if (tid < 260) o = softplus_f(v);      // read strengths
    else if (tid < 324) o = v;                  // write keys (raw)
    else if (tid < 325) o = softplus_f(v);      // write strength
    else if (tid < 389) o = sigmoid_f(v);       // erase vector
    else if (tid < 453) o = v;                  // write vector (raw)
    else if (tid < 459) o = sigmoid_f(v);       // free gates(4), alloc gate, write gate
    else {                                      // read modes: softmax over groups of 3
      int g = (tid - 459) / 3;
      int base = 459 + g * 3;
      float a = s_v[base], b = s_v[base + 1], c = s_v[base + 2];
      float mx = fmaxf(a, fmaxf(b, c));
      float ea = expf(a - mx), eb = expf(b - mx), ec = expf(c - mx);
      o = expf(v - mx) / (ea + eb + ec);
    }
    iface[(size_t)bt * IFSZ + tid] = o;
  }
}

// ---------- per-step: write weights, allocation, usage, memory, precedence ----------
__global__ __launch_bounds__(512) void step_write(
    const float* __restrict__ iface, float* __restrict__ mem,
    const float* __restrict__ rw_old, float* __restrict__ usage,
    const float* __restrict__ prec_old, float* __restrict__ prec_new,
    float* __restrict__ ww_out, int t) {
  int b = blockIdx.x, tid = threadIdx.x;
  int lane = tid & 63, wid = tid >> 6;
  const float* ifc = iface + ((size_t)b * TSTEPS + t) * IFSZ;

  __shared__ float s_wk[64], s_e[64], s_v[64];
  __shared__ float s_sim[512], s_key[512], s_alloc[512], s_ww[512];
  __shared__ int s_idx[512];
  __shared__ float s_red[8];

  if (wid == 0) {  // normalized write key
    float k = ifc[260 + lane];
    float ss = wave_sum(k * k);
    s_wk[lane] = k * rsqrtf(ss + EPSC);
  } else if (wid == 1) {
    s_e[lane] = ifc[325 + lane];   // erase (sigmoided)
    s_v[lane] = ifc[389 + lane];   // write vector
  }
  __syncthreads();

  // --- write content weights: cosine sim + softmax ---
  int n = tid;
  const float4* mrow = (const float4*)(mem + ((size_t)b * NCELLS + n) * WORD_SZ);
  float msum = 0.f, dot = 0.f;
#pragma unroll
  for (int i = 0; i < 16; i++) {
    float4 m4 = mrow[i];
    msum = fmaf(m4.x, m4.x, fmaf(m4.y, m4.y, fmaf(m4.z, m4.z, fmaf(m4.w, m4.w, msum))));
    dot = fmaf(m4.x, s_wk[4 * i], fmaf(m4.y, s_wk[4 * i + 1],
          fmaf(m4.z, s_wk[4 * i + 2], fmaf(m4.w, s_wk[4 * i + 3], dot))));
  }
  float wstr = ifc[324];
  float sim = dot * rsqrtf(msum + EPSC) * wstr;
  float mx = block_max(sim, s_red, tid);
  float e = expf(sim - mx);
  float ssum = block_sum(e, s_red, tid);
  float wcw = e / ssum;
  s_sim[n] = wcw;

  // --- allocation: stable ascending sort of usage (tie-break = index) ---
  float un = usage[(size_t)b * NCELLS + n];
  s_key[n] = un;
  s_idx[n] = n;
  __syncthreads();
  for (int k = 2; k <= 512; k <<= 1) {
    for (int j = k >> 1; j > 0; j >>= 1) {
      int ixj = tid ^ j;
      if (ixj > tid) {
        float a = s_key[tid], bb = s_key[ixj];
        int ia = s_idx[tid], ib = s_idx[ixj];
        bool agb = (a > bb) || (a == bb && ia > ib);  // total order, no ties
        bool up = ((tid & k) == 0);
        if (up ? agb : !agb) {
          s_key[tid] = bb; s_key[ixj] = a;
          s_idx[tid] = ib; s_idx[ixj] = ia;
        }
      }
      __syncthreads();
    }
  }
  // inclusive cumprod scan of sorted usage
  s_alloc[n] = s_key[n];
  __syncthreads();
  for (int off = 1; off < 512; off <<= 1) {
    float vv = s_alloc[n];
    float mm = (n >= off) ? s_alloc[n - off] : 1.f;
    __syncthreads();
    s_alloc[n] = vv * mm;
    __syncthreads();
  }
  {
    float su = s_key[n];
    float ex = (n == 0) ? 1.f : s_alloc[n - 1];
    int oi = s_idx[n];
    __syncthreads();
    s_key[oi] = (1.f - su) * ex;  // scatter back to original order
    __syncthreads();
  }
  float allocv = s_key[n];

  // --- write weights ---
  float ag = ifc[457], wg = ifc[458];
  float wwn = wg * (ag * allocv + (1.f - ag) * wcw);
  s_ww[n] = wwn;
  ww_out[(size_t)b * NCELLS + n] = wwn;

  // --- usage update ---
  float u = un + wwn - un * wwn;
  float psi = 1.f;
#pragma unroll
  for (int r = 0; r < 4; r++) {
    float fg = ifc[453 + r];
    psi *= (1.f - fg * rw_old[((size_t)b * RHEADS + r) * NCELLS + n]);
  }
  usage[(size_t)b * NCELLS + n] = u * psi;

  // --- precedence ---
  float sw = block_sum(wwn, s_red, tid);
  prec_new[(size_t)b * NCELLS + n] = (1.f - sw) * prec_old[(size_t)b * NCELLS + n] + wwn;

  // --- memory erase + write (in place; all sim reads already done) ---
  float* mbase = mem + (size_t)b * NCELLS * WORD_SZ;
#pragma unroll 4
  for (int kk = 0; kk < 64; kk++) {
    int flat = tid + kk * 512;
    int nn = flat >> 6, w = flat & 63;
    float mv = mbase[flat];
    mbase[flat] = mv * (1.f - s_ww[nn] * s_e[w]) + s_ww[nn] * s_v[w];
  }
}

// ---------- per-step: link update (in place) + fused fwd/bwd matvecs ----------
__global__ __launch_bounds__(512) void link_kernel(
    float* __restrict__ link, const float* __restrict__ ww,
    const float* __restrict__ prec_old, const float* __restrict__ rw_old,
    float* __restrict__ fwd, float* __restrict__ bwdp) {
  int stripe = blockIdx.x;  // 0..15 (32 rows each)
  int b = blockIdx.y;
  int tid = threadIdx.x, lane = tid & 63, wid = tid >> 6;
  __shared__ float s_ws[512], s_prec[512], s_rw[4][512], s_bp[4][512];
  s_ws[tid] = ww[(size_t)b * NCELLS + tid];
  s_prec[tid] = prec_old[(size_t)b * NCELLS + tid];
#pragma unroll
  for (int r = 0; r < 4; r++) {
    s_rw[r][tid] = rw_old[((size_t)b * RHEADS + r) * NCELLS + tid];
    s_bp[r][tid] = 0.f;
  }
  __syncthreads();

  float bc[4][8];
#pragma unroll
  for (int r = 0; r < 4; r++)
#pragma unroll
    for (int jj = 0; jj < 8; jj++) bc[r][jj] = 0.f;

  float* lbase = link + (size_t)b * NCELLS * NCELLS;
#pragma unroll
  for (int rr = 0; rr < 4; rr++) {
    int i = stripe * 32 + wid * 4 + rr;
    float wsi = s_ws[i];
    float rwi[4];
#pragma unroll
    for (int r = 0; r < 4; r++) rwi[r] = s_rw[r][i];
    float facc[4] = {0.f, 0.f, 0.f, 0.f};
    float* lr = lbase + (size_t)i * NCELLS;
#pragma unroll
    for (int jj = 0; jj < 8; jj++) {
      int j = jj * 64 + lane;
      float l = lr[j];
      float ln = (1.f - wsi - s_ws[j]) * l + wsi * s_prec[j];
      if (j == i) ln = 0.f;
      lr[j] = ln;
#pragma unroll
      for (int r = 0; r < 4; r++) {
        facc[r] = fmaf(ln, s_rw[r][j], facc[r]);   // fwd: row reduce
        bc[r][jj] = fmaf(ln, rwi[r], bc[r][jj]);   // bwd: column partial
      }
    }
#pragma unroll
    for (int r = 0; r < 4; r++) facc[r] = wave_sum(facc[r]);
    if (lane == 0) {
#pragma unroll
      for (int r = 0; r < 4; r++) fwd[((size_t)b * RHEADS + r) * NCELLS + i] = facc[r];
    }
  }
  // deterministic cross-wave combine of bwd column partials
  for (int wv = 0; wv < 8; wv++) {
    if (wid == wv) {
#pragma unroll
      for (int r = 0; r < 4; r++)
#pragma unroll
        for (int jj = 0; jj < 8; jj++) s_bp[r][jj * 64 + lane] += bc[r][jj];
    }
    __syncthreads();
  }
#pragma unroll
  for (int r = 0; r < 4; r++)
    bwdp[(((size_t)stripe * BATCH + b) * RHEADS + r) * NCELLS + tid] = s_bp[r][tid];
}

// ---------- per-step: read weights + read words ----------
__global__ __launch_bounds__(512) void read_kernel(
    const float* __restrict__ iface, const float* __restrict__ mem,
    const float* __restrict__ fwd, const float* __restrict__ bwdp,
    float* __restrict__ rw_new, float* __restrict__ out, int t) {
  int b = blockIdx.x, tid = threadIdx.x, lane = tid & 63, wid = tid >> 6;
  const float* ifc = iface + ((size_t)b * TSTEPS + t) * IFSZ;
  __shared__ float s_rk[4][64];
  __shared__ float s_rw[4][512];
  __shared__ float s_part[8][4][64];
  __shared__ float s_red[8];

  if (wid < 4) {  // normalized read keys, one wave per head
    float k = ifc[wid * 64 + lane];
    float ss = wave_sum(k * k);
    s_rk[wid][lane] = k * rsqrtf(ss + EPSC);
  }
  __syncthreads();

  int n = tid;
  const float4* mrow = (const float4*)(mem + ((size_t)b * NCELLS + n) * WORD_SZ);
  float msum = 0.f;
  float d[4] = {0.f, 0.f, 0.f, 0.f};
#pragma unroll
  for (int i = 0; i < 16; i++) {
    float4 m4 = mrow[i];
    msum = fmaf(m4.x, m4.x, fmaf(m4.y, m4.y, fmaf(m4.z, m4.z, fmaf(m4.w, m4.w, msum))));
#pragma unroll
    for (int r = 0; r < 4; r++) {
      d[r] = fmaf(m4.x, s_rk[r][4 * i], fmaf(m4.y, s_rk[r][4 * i + 1],
             fmaf(m4.z, s_rk[r][4 * i + 2], fmaf(m4.w, s_rk[r][4 * i + 3], d[r]))));
    }
  }
  float minv = rsqrtf(msum + EPSC);
#pragma unroll
  for (int r = 0; r < 4; r++) {
    float strg = ifc[256 + r];  // softplus already applied
    float sim = d[r] * minv * strg;
    float mx = block_max(sim, s_red, tid);
    float e = expf(sim - mx);
    float ssum = block_sum(e, s_red, tid);
    float rcw = e / ssum;
    float bsum = 0.f;
#pragma unroll
    for (int s = 0; s < NSTRIPE; s++)
      bsum += bwdp[(((size_t)s * BATCH + b) * RHEADS + r) * NCELLS + n];
    float f = fwd[((size_t)b * RHEADS + r) * NCELLS + n];
    float m0 = ifc[459 + r * 3 + 0], m1 = ifc[459 + r * 3 + 1], m2 = ifc[459 + r * 3 + 2];
    float nrw = fmaf(m0, bsum, fmaf(m1, rcw, m2 * f));
    s_rw[r][n] = nrw;
    rw_new[((size_t)b * RHEADS + r) * NCELLS + n] = nrw;
  }
  __syncthreads();

  // read words: each wave handles 64 memory rows, partials combined deterministically
  {
    float acc[4] = {0.f, 0.f, 0.f, 0.f};
    const float* mb = mem + (size_t)b * NCELLS * WORD_SZ;
#pragma unroll 8
    for (int k = 0; k < 64; k++) {
      int nn = wid * 64 + k;
      float m = mb[(size_t)nn * WORD_SZ + lane];
#pragma unroll
      for (int r = 0; r < 4; r++) acc[r] = fmaf(s_rw[r][nn], m, acc[r]);
    }
#pragma unroll
    for (int r = 0; r < 4; r++) s_part[wid][r][lane] = acc[r];
  }
  __syncthreads();
  if (tid < 256) {
    int r = tid >> 6, w = tid & 63;
    float a = 0.f;
#pragma unroll
    for (int wv = 0; wv < 8; wv++) a += s_part[wv][r][w];
    out[(((size_t)b * TSTEPS + t) * RHEADS + r) * WORD_SZ + w] = a;
  }
}

// ---------- host ----------
extern "C" void kernel_launch(void* const* d_in, const int* in_sizes, int n_in,
                              void* d_out, int out_size, void* d_ws, size_t ws_size,
                              hipStream_t stream) {
  const float* ctrl = (const float*)d_in[0];
  const float* Wif = (const float*)d_in[1];
  const float* bif = (const float*)d_in[2];
  float* out = (float*)d_out;

  float* p = (float*)d_ws;
  float* link = p;    p += (size_t)BATCH * NCELLS * NCELLS;           // 4,194,304
  float* mem = p;     p += (size_t)BATCH * NCELLS * WORD_SZ;          //   524,288
  float* iface = p;   p += (size_t)BATCH * TSTEPS * IFSZ;             //   241,152
  float* rwb0 = p;    p += (size_t)BATCH * RHEADS * NCELLS;           //    32,768
  float* rwb1 = p;    p += (size_t)BATCH * RHEADS * NCELLS;
  float* precb0 = p;  p += (size_t)BATCH * NCELLS;
  float* precb1 = p;  p += (size_t)BATCH * NCELLS;
  float* usage = p;   p += (size_t)BATCH * NCELLS;
  float* wwb = p;     p += (size_t)BATCH * NCELLS;
  float* fwdb = p;    p += (size_t)BATCH * RHEADS * NCELLS;
  float* bwdp = p;    p += (size_t)NSTRIPE * BATCH * RHEADS * NCELLS; //   524,288
  // total ~5.62M floats = ~22.5 MB of workspace

  float* rwb[2] = {rwb0, rwb1};
  float* precb[2] = {precb0, precb1};

  hipLaunchKernelGGL(init_kernel, dim3(2048), dim3(256), 0, stream,
                     link, mem, rwb[0], usage, precb[0]);
  hipLaunchKernelGGL(iface_kernel, dim3(BATCH * TSTEPS), dim3(512), 0, stream,
                     ctrl, Wif, bif, iface);
  int cur = 0;
  for (int t = 0; t < TSTEPS; t++) {
    hipLaunchKernelGGL(step_write, dim3(BATCH), dim3(512), 0, stream,
                       iface, mem, rwb[cur], usage, precb[cur], precb[1 - cur], wwb, t);
    hipLaunchKernelGGL(link_kernel, dim3(NSTRIPE, BATCH), dim3(512), 0, stream,
                       link, wwb, precb[cur], rwb[cur], fwdb, bwdp);
    hipLaunchKernelGGL(read_kernel, dim3(BATCH), dim3(512), 0, stream,
                       iface, mem, fwdb, bwdp, rwb[1 - cur], out, t);
    cur ^= 1;
  }
}

// Round 2
// 1058.718 us; speedup vs baseline: 1.6821x; 1.6821x over previous
//
#include <hip/hip_runtime.h>

#define NCELLS 512
#define WORD_SZ 64
#define RHEADS 4
#define BATCH 16
#define TSTEPS 32
#define IFSZ 471
#define EPSC 1e-8f
#define NSTRIPE 16

// ---------- helpers ----------
__device__ __forceinline__ float wave_sum(float v) {
#pragma unroll
  for (int m = 32; m >= 1; m >>= 1) v += __shfl_xor(v, m, 64);
  return v;
}
__device__ __forceinline__ float wave_max(float v) {
#pragma unroll
  for (int m = 32; m >= 1; m >>= 1) v = fmaxf(v, __shfl_xor(v, m, 64));
  return v;
}
__device__ __forceinline__ float block_sum(float v, float* s_red, int tid) {
  float w = wave_sum(v);
  if ((tid & 63) == 0) s_red[tid >> 6] = w;
  __syncthreads();
  float tot = 0.f;
#pragma unroll
  for (int i = 0; i < 8; i++) tot += s_red[i];
  __syncthreads();
  return tot;
}
__device__ __forceinline__ float block_max(float v, float* s_red, int tid) {
  float w = wave_max(v);
  if ((tid & 63) == 0) s_red[tid >> 6] = w;
  __syncthreads();
  float tot = s_red[0];
#pragma unroll
  for (int i = 1; i < 8; i++) tot = fmaxf(tot, s_red[i]);
  __syncthreads();
  return tot;
}
__device__ __forceinline__ float softplus_f(float x) {
  return fmaxf(x, 0.f) + log1pf(expf(-fabsf(x)));
}
__device__ __forceinline__ float sigmoid_f(float x) {
  return 1.f / (1.f + expf(-x));
}

// ---------- init: state slot 0 + t=0 ww ingredients ----------
__global__ void init_kernel(float* link, float* mem, float* rw, float* usage,
                            float* prec, float* wcwb, float* ppb) {
  size_t i = (size_t)blockIdx.x * blockDim.x + threadIdx.x;
  size_t stride = (size_t)gridDim.x * blockDim.x;
  const size_t nlink = (size_t)BATCH * NCELLS * NCELLS;
  const size_t nmem = (size_t)BATCH * NCELLS * WORD_SZ;
  const size_t nrw = (size_t)BATCH * RHEADS * NCELLS;
  const size_t nu = (size_t)BATCH * NCELLS;
  for (size_t x = i; x < nlink; x += stride) link[x] = 0.f;
  for (size_t x = i; x < nmem; x += stride) mem[x] = 0.f;
  for (size_t x = i; x < nrw; x += stride) rw[x] = 1.f / NCELLS;
  for (size_t x = i; x < nu; x += stride) {
    usage[x] = 0.f; prec[x] = 0.f;
    wcwb[x] = 1.f / NCELLS;                       // softmax of zeros
    ppb[0 * nu + x] = ((x & (NCELLS - 1)) == 0) ? 1.f : 0.f;  // alloc = e0
    ppb[1 * nu + x] = 1.f;
    ppb[2 * nu + x] = 1.f;
    ppb[3 * nu + x] = 1.f;
  }
}

// ---------- interface GEMM + activations (once) ----------
__global__ __launch_bounds__(512) void iface_kernel(
    const float* __restrict__ ctrl, const float* __restrict__ W,
    const float* __restrict__ bif, float* __restrict__ iface) {
  int bt = blockIdx.x;
  int tid = threadIdx.x;
  __shared__ float s_ctrl[512];
  __shared__ float s_v[IFSZ];
  s_ctrl[tid] = ctrl[(size_t)bt * 512 + tid];
  __syncthreads();
  if (tid < IFSZ) {
    float acc = bif[tid];
#pragma unroll 8
    for (int k = 0; k < 512; k++) acc = fmaf(s_ctrl[k], W[(size_t)k * IFSZ + tid], acc);
    s_v[tid] = acc;
  }
  __syncthreads();
  if (tid < IFSZ) {
    float v = s_v[tid];
    float o;
    if (tid < 256) o = v;
    else if (tid < 260) o = softplus_f(v);
    else if (tid < 324) o = v;
    else if (tid < 325) o = softplus_f(v);
    else if (tid < 389) o = sigmoid_f(v);
    else if (tid < 453) o = v;
    else if (tid < 459) o = sigmoid_f(v);
    else {
      int g = (tid - 459) / 3;
      int base = 459 + g * 3;
      float a = s_v[base], b = s_v[base + 1], c = s_v[base + 2];
      float mx = fmaxf(a, fmaxf(b, c));
      float ea = expf(a - mx), eb = expf(b - mx), ec = expf(c - mx);
      o = expf(v - mx) / (ea + eb + ec);
    }
    iface[(size_t)bt * IFSZ + tid] = o;
  }
}

// ---------- K1: combine ww + link update + fwd/bwd + mem/usage/prec ----------
__global__ __launch_bounds__(512) void step_link(
    const float* __restrict__ iface,
    const float* __restrict__ mem_old, float* __restrict__ mem_new,
    const float* __restrict__ usage_old, float* __restrict__ usage_new,
    const float* __restrict__ prec_old, float* __restrict__ prec_new,
    const float* __restrict__ rw_old,
    const float* __restrict__ wcwb, const float* __restrict__ ppb,
    float* __restrict__ link, float* __restrict__ fwd, float* __restrict__ bwdp,
    int t) {
  int stripe = blockIdx.x, b = blockIdx.y;
  int tid = threadIdx.x, lane = tid & 63, wid = tid >> 6;
  int n = tid;
  const float* ifc = iface + ((size_t)b * TSTEPS + t) * IFSZ;

  __shared__ float s_e[64], s_v[64];
  __shared__ float s_ww[512], s_prec[512], s_rw4[4][512];
  __shared__ float s_bpB[4][4][512];  // 32 KB: bwd tree combine
  __shared__ float s_red[8];

  if (wid == 0 && stripe == 0) { s_e[lane] = ifc[325 + lane]; s_v[lane] = ifc[389 + lane]; }

  size_t bn = (size_t)b * NCELLS;
  const size_t BN = (size_t)BATCH * NCELLS;
  float u_n = usage_old[bn + n];
  float wcw = wcwb[bn + n];
  float p01 = ppb[0 * BN + bn + n] * ppb[1 * BN + bn + n];
  float p23 = ppb[2 * BN + bn + n] * ppb[3 * BN + bn + n];
  float allocv = (1.f - u_n) * (p01 * p23);
  float ag = ifc[457], wg = ifc[458];
  float wwn = wg * (ag * allocv + (1.f - ag) * wcw);
  s_ww[n] = wwn;
  s_prec[n] = prec_old[bn + n];
#pragma unroll
  for (int r = 0; r < 4; r++) s_rw4[r][n] = rw_old[(bn * RHEADS) + (size_t)r * NCELLS + n];
  __syncthreads();

  // --- link stripe update, fwd row-reduce, bwd column partials ---
  float* lbase = link + (size_t)b * NCELLS * NCELLS;
  int i0 = stripe * 32 + wid * 4;
  float wsi[4], rwi[4][4];
#pragma unroll
  for (int rr = 0; rr < 4; rr++) {
    wsi[rr] = s_ww[i0 + rr];
#pragma unroll
    for (int r = 0; r < 4; r++) rwi[rr][r] = s_rw4[r][i0 + rr];
  }
  float facc[4][4];
  float bc[4][8];
#pragma unroll
  for (int a = 0; a < 4; a++)
#pragma unroll
    for (int c = 0; c < 4; c++) facc[a][c] = 0.f;
#pragma unroll
  for (int a = 0; a < 4; a++)
#pragma unroll
    for (int c = 0; c < 8; c++) bc[a][c] = 0.f;

#pragma unroll
  for (int jj = 0; jj < 8; jj++) {
    int j = jj * 64 + lane;
    float swj = s_ww[j], spj = s_prec[j];
    float srw0 = s_rw4[0][j], srw1 = s_rw4[1][j], srw2 = s_rw4[2][j], srw3 = s_rw4[3][j];
#pragma unroll
    for (int rr = 0; rr < 4; rr++) {
      float* lp = lbase + (size_t)(i0 + rr) * NCELLS + j;
      float l = *lp;
      float ln = fmaf(1.f - wsi[rr] - swj, l, wsi[rr] * spj);
      if (j == i0 + rr) ln = 0.f;
      *lp = ln;
      facc[rr][0] = fmaf(ln, srw0, facc[rr][0]);
      facc[rr][1] = fmaf(ln, srw1, facc[rr][1]);
      facc[rr][2] = fmaf(ln, srw2, facc[rr][2]);
      facc[rr][3] = fmaf(ln, srw3, facc[rr][3]);
      bc[0][jj] = fmaf(ln, rwi[rr][0], bc[0][jj]);
      bc[1][jj] = fmaf(ln, rwi[rr][1], bc[1][jj]);
      bc[2][jj] = fmaf(ln, rwi[rr][2], bc[2][jj]);
      bc[3][jj] = fmaf(ln, rwi[rr][3], bc[3][jj]);
    }
  }
#pragma unroll
  for (int rr = 0; rr < 4; rr++) {
#pragma unroll
    for (int r = 0; r < 4; r++) facc[rr][r] = wave_sum(facc[rr][r]);
    if (lane == 0) {
#pragma unroll
      for (int r = 0; r < 4; r++)
        fwd[((size_t)b * RHEADS + r) * NCELLS + (i0 + rr)] = facc[rr][r];
    }
  }
  // bwd: 2-round LDS tree (waves w and w+4 pair up), then 4-way column sum
  if (wid >= 4) {
#pragma unroll
    for (int r = 0; r < 4; r++)
#pragma unroll
      for (int jj = 0; jj < 8; jj++) s_bpB[wid - 4][r][jj * 64 + lane] = bc[r][jj];
  }
  __syncthreads();
  if (wid < 4) {
#pragma unroll
    for (int r = 0; r < 4; r++)
#pragma unroll
      for (int jj = 0; jj < 8; jj++) s_bpB[wid][r][jj * 64 + lane] += bc[r][jj];
  }
  __syncthreads();
#pragma unroll
  for (int r = 0; r < 4; r++) {
    float a = ((s_bpB[0][r][tid] + s_bpB[1][r][tid]) + (s_bpB[2][r][tid] + s_bpB[3][r][tid]));
    bwdp[(((size_t)stripe * BATCH + b) * RHEADS + r) * NCELLS + tid] = a;
  }

  // --- memory erase+write (ping-pong, stripe 0 only) ---
  if (stripe == 0) {
    const float* mo = mem_old + (size_t)b * NCELLS * WORD_SZ;
    float* mn = mem_new + (size_t)b * NCELLS * WORD_SZ;
#pragma unroll 4
    for (int kk = 0; kk < 64; kk++) {
      int flat = tid + kk * 512;
      int nn = flat >> 6, w = flat & 63;
      mn[flat] = fmaf(mo[flat], (1.f - s_ww[nn] * s_e[w]), s_ww[nn] * s_v[w]);
    }
  }
  // --- usage + precedence (stripe 15 only; double-buffered) ---
  if (stripe == 15) {
    float u = u_n + wwn - u_n * wwn;
    float psi = 1.f;
#pragma unroll
    for (int r = 0; r < 4; r++) psi *= (1.f - ifc[453 + r] * s_rw4[r][n]);
    usage_new[bn + n] = u * psi;
    float sw = block_sum(wwn, s_red, tid);
    prec_new[bn + n] = (1.f - sw) * s_prec[n] + wwn;
  }
}

// ---------- K2: read heads + read words + next-step ww ingredients ----------
__global__ __launch_bounds__(512) void read_step(
    const float* __restrict__ iface, const float* __restrict__ mem_new,
    const float* __restrict__ fwd, const float* __restrict__ bwdp,
    const float* __restrict__ usage_cur,
    float* __restrict__ rw_new, float* __restrict__ wcwb, float* __restrict__ ppb,
    float* __restrict__ out, int t) {
  int r = blockIdx.x, b = blockIdx.y;
  int tid = threadIdx.x, lane = tid & 63, wid = tid >> 6;
  int n = tid;
  const float* ifc = iface + ((size_t)b * TSTEPS + t) * IFSZ;
  bool have_next = (t + 1 < TSTEPS);
  const float* ifc2 = iface + ((size_t)b * TSTEPS + (have_next ? t + 1 : t)) * IFSZ;

  __shared__ float s_k[64], s_wk[64];
  __shared__ __align__(16) float s_u[512];
  __shared__ float s_rw[512];
  __shared__ float s_part[8][64];
  __shared__ float s_red[8];

  if (wid == 0) {
    float k = ifc[r * 64 + lane];
    float ss = wave_sum(k * k);
    s_k[lane] = k * rsqrtf(ss + EPSC);
  } else if (wid == 1 && have_next) {
    float k = ifc2[260 + lane];
    float ss = wave_sum(k * k);
    s_wk[lane] = k * rsqrtf(ss + EPSC);
  }
  if (have_next) s_u[tid] = usage_cur[(size_t)b * NCELLS + tid];
  __syncthreads();

  // content sim for this head (+ write-key sim for t+1, folded into same pass, r==0 only)
  const float4* mrow = (const float4*)(mem_new + ((size_t)b * NCELLS + n) * WORD_SZ);
  bool do_w = (r == 0) && have_next;
  float msum = 0.f, dot = 0.f, dotw = 0.f;
#pragma unroll
  for (int i = 0; i < 16; i++) {
    float4 m4 = mrow[i];
    msum = fmaf(m4.x, m4.x, fmaf(m4.y, m4.y, fmaf(m4.z, m4.z, fmaf(m4.w, m4.w, msum))));
    dot = fmaf(m4.x, s_k[4 * i], fmaf(m4.y, s_k[4 * i + 1],
          fmaf(m4.z, s_k[4 * i + 2], fmaf(m4.w, s_k[4 * i + 3], dot))));
    if (do_w)
      dotw = fmaf(m4.x, s_wk[4 * i], fmaf(m4.y, s_wk[4 * i + 1],
             fmaf(m4.z, s_wk[4 * i + 2], fmaf(m4.w, s_wk[4 * i + 3], dotw))));
  }
  float minv = rsqrtf(msum + EPSC);
  float sim = dot * minv * ifc[256 + r];
  float mx = block_max(sim, s_red, tid);
  float e = expf(sim - mx);
  float ssum = block_sum(e, s_red, tid);
  float rcw = e / ssum;
  float bsum = 0.f;
#pragma unroll
  for (int s = 0; s < NSTRIPE; s++)
    bsum += bwdp[(((size_t)s * BATCH + b) * RHEADS + r) * NCELLS + n];
  float f = fwd[((size_t)b * RHEADS + r) * NCELLS + n];
  float m0 = ifc[459 + r * 3], m1 = ifc[459 + r * 3 + 1], m2 = ifc[459 + r * 3 + 2];
  float nrw = fmaf(m0, bsum, fmaf(m1, rcw, m2 * f));
  s_rw[n] = nrw;
  rw_new[((size_t)b * RHEADS + r) * NCELLS + n] = nrw;
  __syncthreads();

  // read words: wave w covers rows [64w, 64w+64)
  float acc = 0.f;
  const float* mb = mem_new + (size_t)b * NCELLS * WORD_SZ;
#pragma unroll 8
  for (int k = 0; k < 64; k++) {
    int nn = wid * 64 + k;
    acc = fmaf(s_rw[nn], mb[(size_t)nn * WORD_SZ + lane], acc);
  }
  s_part[wid][lane] = acc;
  __syncthreads();
  if (tid < 64) {
    float a = 0.f;
#pragma unroll
    for (int w = 0; w < 8; w++) a += s_part[w][tid];
    out[(((size_t)b * TSTEPS + t) * RHEADS + r) * WORD_SZ + tid] = a;
  }

  // next-step ww ingredients: allocation partial product over slice [128r,128r+128)
  if (have_next) {
    float un = s_u[n];
    int base = r * 128;
    float p0 = 1.f, p1 = 1.f, p2 = 1.f, p3 = 1.f;
#pragma unroll 8
    for (int j = 0; j < 128; j += 4) {
      float4 u4 = *(const float4*)&s_u[base + j];
      int ja = base + j;
      p0 *= (u4.x < un || (u4.x == un && (ja + 0) < n)) ? u4.x : 1.f;
      p1 *= (u4.y < un || (u4.y == un && (ja + 1) < n)) ? u4.y : 1.f;
      p2 *= (u4.z < un || (u4.z == un && (ja + 2) < n)) ? u4.z : 1.f;
      p3 *= (u4.w < un || (u4.w == un && (ja + 3) < n)) ? u4.w : 1.f;
    }
    ppb[((size_t)r * BATCH + b) * NCELLS + n] = (p0 * p1) * (p2 * p3);
    if (r == 0) {  // write-content softmax for t+1 (uses mem(t), key(t+1))
      float simw = dotw * minv * ifc2[324];
      float mxw = block_max(simw, s_red, tid);
      float ew = expf(simw - mxw);
      float ssw = block_sum(ew, s_red, tid);
      wcwb[(size_t)b * NCELLS + n] = ew / ssw;
    }
  }
}

// ---------- host ----------
extern "C" void kernel_launch(void* const* d_in, const int* in_sizes, int n_in,
                              void* d_out, int out_size, void* d_ws, size_t ws_size,
                              hipStream_t stream) {
  const float* ctrl = (const float*)d_in[0];
  const float* Wif = (const float*)d_in[1];
  const float* bif = (const float*)d_in[2];
  float* out = (float*)d_out;

  float* p = (float*)d_ws;
  float* link = p;   p += (size_t)BATCH * NCELLS * NCELLS;
  float* mem0 = p;   p += (size_t)BATCH * NCELLS * WORD_SZ;
  float* mem1 = p;   p += (size_t)BATCH * NCELLS * WORD_SZ;
  float* iface = p;  p += (size_t)BATCH * TSTEPS * IFSZ;
  float* rw0 = p;    p += (size_t)BATCH * RHEADS * NCELLS;
  float* rw1 = p;    p += (size_t)BATCH * RHEADS * NCELLS;
  float* us0 = p;    p += (size_t)BATCH * NCELLS;
  float* us1 = p;    p += (size_t)BATCH * NCELLS;
  float* pr0 = p;    p += (size_t)BATCH * NCELLS;
  float* pr1 = p;    p += (size_t)BATCH * NCELLS;
  float* fwdb = p;   p += (size_t)BATCH * RHEADS * NCELLS;
  float* bwdp = p;   p += (size_t)NSTRIPE * BATCH * RHEADS * NCELLS;
  float* wcwb = p;   p += (size_t)BATCH * NCELLS;
  float* ppb = p;    p += (size_t)4 * BATCH * NCELLS;

  float* mem[2] = {mem0, mem1};
  float* rw[2] = {rw0, rw1};
  float* us[2] = {us0, us1};
  float* pr[2] = {pr0, pr1};

  hipLaunchKernelGGL(init_kernel, dim3(2048), dim3(256), 0, stream,
                     link, mem[0], rw[0], us[0], pr[0], wcwb, ppb);
  hipLaunchKernelGGL(iface_kernel, dim3(BATCH * TSTEPS), dim3(512), 0, stream,
                     ctrl, Wif, bif, iface);
  for (int t = 0; t < TSTEPS; t++) {
    int cu = t & 1;
    hipLaunchKernelGGL(step_link, dim3(NSTRIPE, BATCH), dim3(512), 0, stream,
                       iface, mem[cu], mem[cu ^ 1], us[cu], us[cu ^ 1],
                       pr[cu], pr[cu ^ 1], rw[cu], wcwb, ppb,
                       link, fwdb, bwdp, t);
    hipLaunchKernelGGL(read_step, dim3(RHEADS, BATCH), dim3(512), 0, stream,
                       iface, mem[cu ^ 1], fwdb, bwdp, us[cu ^ 1],
                       rw[cu ^ 1], wcwb, ppb, out, t);
  }
}